// Round 11
// baseline (113.412 us; speedup 1.0000x reference)
//
#include <hip/hip_runtime.h>
#include <cstdint>
#include <cstddef>

#define TPB  256
#define TILES 2
#define SPAN (TPB * TILES)   // 512 anchors per block
#define MAXT 128             // max targets supported (T=64 here)
#define BIGC 1e18f           // far-away point box for invalid targets

// ---------------------------------------------------------------------------
// Focal-term helpers (hardware exp2/log2/rcp).
// f_bg(x) = 0.25 sigmoid(x)^2 softplus(x); f_fg = 0.75 (1-sig)^2 softplus(-x)
// f_bg4 returns RAW sum sigmoid^2 * softplus(x)/ln2 (K_BG applied once).
// ---------------------------------------------------------------------------
#define K_BG 0.17328679514f   // 0.25 * ln(2)

__device__ __forceinline__ float f_bg4(float4 v) {
    float r = 0.f;
    const float xs[4] = {v.x, v.y, v.z, v.w};
    #pragma unroll
    for (int i = 0; i < 4; ++i) {
        const float x  = xs[i];
        const float u  = x * 1.44269504089f;
        const float em = __builtin_amdgcn_exp2f(-fabsf(u));  // e^-|x|
        const float oe = 1.f + em;
        const float l2 = __builtin_amdgcn_logf(oe);          // log2(1+e^-|x|)
        const float s  = __builtin_amdgcn_rcpf(oe);          // sigmoid(|x|)
        const float sp2 = fmaxf(u, 0.f) + l2;                // softplus(x)/ln2
        const float p  = (x >= 0.f) ? s : (1.f - s);
        r = fmaf(p * p, sp2, r);
    }
    return r;
}

__device__ __forceinline__ float f_fg_minus_bg(float x) {
    const float ax = fabsf(x);
    const float em = __builtin_amdgcn_exp2f(ax * -1.44269504089f);
    const float oe = 1.f + em;
    const float l  = __builtin_amdgcn_logf(oe) * 0.69314718056f;
    const float s  = __builtin_amdgcn_rcpf(oe);
    const float sp_p = (x >= 0.f) ? (x + l) : l;
    const float sp_n = sp_p - x;
    const float p  = (x >= 0.f) ? s : (1.f - s);
    const float q  = 1.f - p;
    return 0.75f * q * q * sp_n - 0.25f * p * p * sp_p;
}

struct AGeom { float tl0, tl1, br0, br1, area_eps; };

__device__ __forceinline__ void iou_step(const AGeom& g, const float4 ta, int tt,
                                         float& bI, float& bU, int& besti) {
    const float tl0 = fmaxf(g.tl0, ta.x);
    const float tl1 = fmaxf(g.tl1, ta.y);
    const float br0 = fminf(g.br0, ta.z);
    const float br1 = fminf(g.br1, ta.w);
    const float sz0 = fmaxf(br0 - tl0, 0.0f);
    const float sz1 = fmaxf(br1 - tl1, 0.0f);
    const float inter = sz0 * sz1;
    const float tarea = (ta.z - ta.x) * (ta.w - ta.y);
    const float uni = g.area_eps + tarea - inter;
    const bool upd = inter * bU > bI * uni;   // iou_t > iou_best, exact compare
    bI = upd ? inter : bI;
    bU = upd ? uni   : bU;
    besti = upd ? tt : besti;
}

// ---------------------------------------------------------------------------
// Fused kernel. Per block = 512 contiguous anchors (2 tiles) of one image.
//   0a: issue first 5 focal float4 loads
//   0b: stage targets -> LDS; block bbox over BOTH tiles' anchors
//   0c: wave 0 prunes targets vs block bbox -> compacted active list
//   1 : single 8-group pipelined loop: {prefetch 5 | f_bg x20 | IoU chunk},
//       groups 0-3 = tile0 anchor, groups 4-7 = tile1 anchor (unrolled)
//   2 : classify both anchors, smooth-L1 for positives
//   3 : merged ballot compaction (512), sparse corrections, one partial write.
// __launch_bounds__(256,4): VGPR cap 128 -> 16 waves/CU.  No atomics.
// ---------------------------------------------------------------------------
template<int C4T>
__global__ __launch_bounds__(TPB, 4)
void fused_kernel(const float* __restrict__ bbox_preds,  // [B,A,4]
                  const float* __restrict__ bbox_tgts,   // [B,T,4] tlbr
                  const int*   __restrict__ clas_tgts,   // [B,T]
                  const float* __restrict__ anchors,     // [A,4] cthw
                  const float* __restrict__ clas_preds,  // [B,A,C]
                  int A, int T, int C4rt,
                  float* __restrict__ np_p,   // [B*nblk]
                  float* __restrict__ bb_p,   // [B*nblk]
                  float* __restrict__ cl_p,   // [B*nblk]
                  int nblk)
{
    const int C4  = (C4T > 0) ? C4T : C4rt;
    const int b   = blockIdx.y;
    const int a0  = blockIdx.x * SPAN;
    const int tid = threadIdx.x;
    const int lane = tid & 63;
    const int wid  = tid >> 6;
    const int nA  = min(SPAN, A - a0);
    const bool in[2] = { a0 + tid < A, a0 + TPB + tid < A };

    const float4* tile = reinterpret_cast<const float4*>(clas_preds)
                         + ((size_t)b * A + a0) * C4;

    // ---- 0a: first prefetch group, ASAP ----
    constexpr int CH  = 5;
    constexpr int NCH = (C4T > 0 ? C4T : 5) / CH;   // 4 for C4=20
    float4 cur[CH];
    if (C4T > 0 && nA == SPAN) {
        #pragma unroll
        for (int i = 0; i < CH; ++i) cur[i] = tile[tid + i * TPB];
    }

    // ---- 0b: stage targets ----
    __shared__ float4 s_ta[MAXT];   // tlbr (point box at BIGC if invalid)
    __shared__ int    s_cls[MAXT];
    for (int i = tid; i < T; i += TPB) {
        const float4 tg = reinterpret_cast<const float4*>(bbox_tgts)[(size_t)b * T + i];
        const int   cl = clas_tgts[(size_t)b * T + i];
        const float c0 = (tg.x + tg.z) * 0.5f, c1 = (tg.y + tg.w) * 0.5f;
        const float s0 = tg.z - tg.x,          s1 = tg.w - tg.y;
        s_ta[i] = (cl > 0) ? make_float4(c0 - s0 * 0.5f, c1 - s1 * 0.5f,
                                         c0 + s0 * 0.5f, c1 + s1 * 0.5f)
                           : make_float4(BIGC, BIGC, BIGC, BIGC);
        s_cls[i] = cl;
    }

    // per-tile anchor geometry
    AGeom geo[2];
    #pragma unroll
    for (int ti = 0; ti < 2; ++ti) {
        float4 anc = make_float4(0.f, 0.f, 1.f, 1.f);
        if (in[ti]) anc = reinterpret_cast<const float4*>(anchors)[a0 + ti * TPB + tid];
        geo[ti].tl0 = anc.x - anc.z * 0.5f;
        geo[ti].tl1 = anc.y - anc.w * 0.5f;
        geo[ti].br0 = anc.x + anc.z * 0.5f;
        geo[ti].br1 = anc.y + anc.w * 0.5f;
        geo[ti].area_eps = anc.z * anc.w + 1e-8f;
    }

    // block bbox over both tiles (OOB lanes neutral)
    float m0 =  1e30f, m1 =  1e30f, M0 = -1e30f, M1 = -1e30f;
    #pragma unroll
    for (int ti = 0; ti < 2; ++ti) if (in[ti]) {
        m0 = fminf(m0, geo[ti].tl0); m1 = fminf(m1, geo[ti].tl1);
        M0 = fmaxf(M0, geo[ti].br0); M1 = fmaxf(M1, geo[ti].br1);
    }
    #pragma unroll
    for (int off = 32; off; off >>= 1) {
        m0 = fminf(m0, __shfl_down(m0, off));
        m1 = fminf(m1, __shfl_down(m1, off));
        M0 = fmaxf(M0, __shfl_down(M0, off));
        M1 = fmaxf(M1, __shfl_down(M1, off));
    }
    __shared__ float s_red[4][TPB / 64];
    if (lane == 0) {
        s_red[0][wid] = m0; s_red[1][wid] = m1;
        s_red[2][wid] = M0; s_red[3][wid] = M1;
    }
    __syncthreads();

    // ---- 0c: wave 0 prunes + compacts targets ----
    __shared__ int s_act[MAXT];
    __shared__ int s_nact;
    if (wid == 0) {
        float bm0 = s_red[0][0], bm1 = s_red[1][0];
        float bM0 = s_red[2][0], bM1 = s_red[3][0];
        #pragma unroll
        for (int w = 1; w < TPB / 64; ++w) {
            bm0 = fminf(bm0, s_red[0][w]); bm1 = fminf(bm1, s_red[1][w]);
            bM0 = fmaxf(bM0, s_red[2][w]); bM1 = fmaxf(bM1, s_red[3][w]);
        }
        bool act = false;
        if (lane < T && T <= 64) {
            const float4 ta = s_ta[lane];
            act = (ta.x <= bM0) && (ta.y <= bM1) && (ta.z >= bm0) && (ta.w >= bm1);
        }
        const unsigned long long ball = __ballot(act);
        if (act) {
            const unsigned long long lm =
                (lane == 63) ? ~0ULL >> 1 : (1ULL << lane) - 1;
            s_act[__popcll(ball & lm)] = lane;
        }
        if (lane == 0) s_nact = __popcll(ball);
    }
    if (T > 64) {   // generic fallback: no pruning
        for (int i = tid; i < T; i += TPB) s_act[i] = i;
        if (tid == 0) s_nact = T;
    }
    __syncthreads();

    const int nact = s_nact;
    float bI[2] = {-1.f, -1.f}, bU[2] = {1.f, 1.f};
    int   besti[2] = {0, 0};

    // ---- phase 1: single pipelined hot loop over both tiles ----
    float raw = 0.f;
    if (C4T > 0 && nA == SPAN) {
        const int cs = (nact + NCH - 1) / NCH;
        #pragma unroll
        for (int g = 0; g < 2 * NCH; ++g) {
            float4 nxt[CH];
            if (g + 1 < 2 * NCH) {
                #pragma unroll
                for (int i = 0; i < CH; ++i)
                    nxt[i] = tile[tid + ((g + 1) * CH + i) * TPB];
            }
            #pragma unroll
            for (int i = 0; i < CH; ++i) raw += f_bg4(cur[i]);
            constexpr int NCHc = NCH;
            const int ai = g / NCHc;          // compile-time after unroll
            const int gg = g - ai * NCHc;
            const int te = min((gg + 1) * cs, nact);
            for (int t = gg * cs; t < te; ++t) {
                const int tt = s_act[t];
                iou_step(geo[ai], s_ta[tt], tt, bI[ai], bU[ai], besti[ai]);
            }
            if (g + 1 < 2 * NCH) {
                #pragma unroll
                for (int i = 0; i < CH; ++i) cur[i] = nxt[i];
            }
        }
    } else {
        // generic path (tail block / unexpected C)
        const int tot = nA * C4;
        for (int j = tid; j < tot; j += TPB)
            raw += f_bg4(tile[j]);
        for (int t = 0; t < nact; ++t) {
            const int tt = s_act[t];
            iou_step(geo[0], s_ta[tt], tt, bI[0], bU[0], besti[0]);
            iou_step(geo[1], s_ta[tt], tt, bI[1], bU[1], besti[1]);
        }
    }

    // ---- phase 2: classify both anchors + smooth-L1 ----
    bool pos[2], ign[2];
    int  cls[2] = {0, 0};
    float sl1 = 0.f;
    #pragma unroll
    for (int ti = 0; ti < 2; ++ti) {
        pos[ti] = in[ti] && (bI[ti] > 0.5f * bU[ti]);
        ign[ti] = in[ti] && !pos[ti] && !(bI[ti] < 0.4f * bU[ti]);
        if (pos[ti]) {
            // rare path: precise logf + divs; anc recomputed from geometry
            const int bi = besti[ti];
            const float4 ta = s_ta[bi];
            cls[ti] = s_cls[bi];
            const float az = geo[ti].br0 - geo[ti].tl0;          // anc h
            const float aw = geo[ti].br1 - geo[ti].tl1;          // anc w
            const float ax = (geo[ti].tl0 + geo[ti].br0) * 0.5f; // anc cy
            const float ay = (geo[ti].tl1 + geo[ti].br1) * 0.5f; // anc cx
            const float tz = ta.z - ta.x, tw = ta.w - ta.y;      // tgt h,w
            const float tx = (ta.x + ta.z) * 0.5f, ty = (ta.y + ta.w) * 0.5f;
            const float4 bp = reinterpret_cast<const float4*>(bbox_preds)
                                  [(size_t)b * A + a0 + ti * TPB + tid];
            const float r0 = ((tx - ax) / az) / 0.1f;
            const float r1 = ((ty - ay) / aw) / 0.1f;
            const float r2 = logf(tz / az + 1e-8f) / 0.2f;
            const float r3 = logf(tw / aw + 1e-8f) / 0.2f;
            const float d0 = bp.x - r0, d1 = bp.y - r1, d2 = bp.z - r2, d3 = bp.w - r3;
            const float a0f = fabsf(d0), a1f = fabsf(d1), a2f = fabsf(d2), a3f = fabsf(d3);
            sl1 += (a0f < 1.f) ? 0.5f * d0 * d0 : a0f - 0.5f;
            sl1 += (a1f < 1.f) ? 0.5f * d1 * d1 : a1f - 0.5f;
            sl1 += (a2f < 1.f) ? 0.5f * d2 * d2 : a2f - 0.5f;
            sl1 += (a3f < 1.f) ? 0.5f * d3 * d3 : a3f - 0.5f;
        }
    }

    // ---- phase 3: merged deterministic compaction over 512 anchors ----
    unsigned long long pb[2], ib[2];
    pb[0] = __ballot(pos[0]); pb[1] = __ballot(pos[1]);
    ib[0] = __ballot(ign[0]); ib[1] = __ballot(ign[1]);

    __shared__ int s_pc[2][TPB / 64], s_ic[2][TPB / 64];
    __shared__ int s_plist[SPAN], s_pcls[SPAN], s_ilist[SPAN];
    if (lane == 0) {
        s_pc[0][wid] = __popcll(pb[0]); s_pc[1][wid] = __popcll(pb[1]);
        s_ic[0][wid] = __popcll(ib[0]); s_ic[1][wid] = __popcll(ib[1]);
    }
    __syncthreads();
    // scan order: tile0 waves 0..3, then tile1 waves 0..3
    int p_off[2] = {0, 0}, i_off[2] = {0, 0}, p_total = 0, i_total = 0;
    #pragma unroll
    for (int ti = 0; ti < 2; ++ti)
        #pragma unroll
        for (int w = 0; w < TPB / 64; ++w) {
            if (ti < 1 || (ti == 1 && true)) {}   // (no-op, clarity)
            if ((ti == 0 && w < wid) || ti < 0) {}
            // offsets: everything before (ti, wid)
            if (ti == 0) { if (w < wid) p_off[0] += s_pc[0][w]; }
            else {
                p_off[1] += (0);  // placeholder
            }
            p_total += s_pc[ti][w];
            i_total += s_ic[ti][w];
        }
    // tile1 offset = total of tile0 + preceding waves of tile1
    {
        int t0p = 0, t0i = 0;
        #pragma unroll
        for (int w = 0; w < TPB / 64; ++w) { t0p += s_pc[0][w]; t0i += s_ic[0][w]; }
        p_off[1] = t0p; i_off[1] = t0i;
        #pragma unroll
        for (int w = 0; w < TPB / 64; ++w) {
            if (w < wid) { p_off[1] += s_pc[1][w]; i_off[1] += s_ic[1][w]; }
        }
        #pragma unroll
        for (int w = 0; w < TPB / 64; ++w) {
            if (w < wid) i_off[0] += s_ic[0][w];
        }
    }
    const unsigned long long lmask = (lane == 63) ? ~0ULL >> 1 : (1ULL << lane) - 1;
    #pragma unroll
    for (int ti = 0; ti < 2; ++ti) {
        if (pos[ti]) {
            const int idx = p_off[ti] + __popcll(pb[ti] & lmask);
            s_plist[idx] = a0 + ti * TPB + tid; s_pcls[idx] = cls[ti];
        }
        if (ign[ti]) {
            const int idx = i_off[ti] + __popcll(ib[ti] & lmask);
            s_ilist[idx] = a0 + ti * TPB + tid;
        }
    }
    __syncthreads();

    // ---- phase 4: sparse corrections ----
    float corr = 0.f;
    for (int j = tid; j < p_total; j += TPB) {
        const int pa = s_plist[j];
        const int pc = s_pcls[j];
        corr += f_fg_minus_bg(clas_preds[((size_t)b * A + pa) * (C4 * 4) + (pc - 1)]);
    }
    const int ig_elems = i_total * C4;   // rare: usually 0
    for (int j = tid; j < ig_elems; j += TPB) {
        const int ii = j / C4;
        const int c4 = j - ii * C4;
        const int ia = s_ilist[ii];
        raw -= f_bg4(reinterpret_cast<const float4*>(clas_preds)
                         [((size_t)b * A + ia) * C4 + c4]);
    }

    // ---- phase 5: block reduction -> one partial per block ----
    float v = sl1;
    float u = fmaf(raw, K_BG, corr);
    #pragma unroll
    for (int off = 32; off; off >>= 1) {
        v += __shfl_down(v, off);
        u += __shfl_down(u, off);
    }
    __shared__ float s_sl1[TPB / 64], s_cl2[TPB / 64];
    if (lane == 0) { s_sl1[wid] = v; s_cl2[wid] = u; }
    __syncthreads();
    if (tid == 0) {
        float tv = 0.f, tu = 0.f;
        #pragma unroll
        for (int w = 0; w < TPB / 64; ++w) { tv += s_sl1[w]; tu += s_cl2[w]; }
        const size_t o = (size_t)b * nblk + blockIdx.x;
        bb_p[o] = tv;
        cl_p[o] = tu;
        np_p[o] = (float)p_total;
    }
}

// ---------------------------------------------------------------------------
// Final reduce: one wave per image, thread 0 emits the scalar.
// ---------------------------------------------------------------------------
__global__ void reduce_kernel(const float* __restrict__ np_p,  // [B*nblk]
                              const float* __restrict__ bb_p,
                              const float* __restrict__ cl_p,
                              int nblk, int Bn,
                              float* __restrict__ out)
{
    const int wid  = threadIdx.x >> 6;
    const int lane = threadIdx.x & 63;
    const int nw   = blockDim.x >> 6;
    __shared__ float s_loss[32];

    float acc = 0.f;
    for (int b = wid; b < Bn; b += nw) {
        float cl = 0.f, bb = 0.f, np = 0.f;
        for (int i = lane; i < nblk; i += 64) {
            const size_t o = (size_t)b * nblk + i;
            np += np_p[o]; bb += bb_p[o]; cl += cl_p[o];
        }
        #pragma unroll
        for (int off = 32; off; off >>= 1) {
            cl += __shfl_down(cl, off);
            bb += __shfl_down(bb, off);
            np += __shfl_down(np, off);
        }
        if (lane == 0)
            acc += bb / fmaxf(4.f * np, 1.f) + cl / fmaxf(np, 1.f);
    }
    if (lane == 0) s_loss[wid] = acc;
    __syncthreads();
    if (threadIdx.x == 0) {
        float v = 0.f;
        for (int w = 0; w < nw; ++w) v += s_loss[w];
        out[0] = v / (float)Bn;
    }
}

// ---------------------------------------------------------------------------
extern "C" void kernel_launch(void* const* d_in, const int* in_sizes, int n_in,
                              void* d_out, int out_size, void* d_ws, size_t ws_size,
                              hipStream_t stream)
{
    const float* clas_preds = (const float*)d_in[0];
    const float* bbox_preds = (const float*)d_in[1];
    const float* bbox_tgts  = (const float*)d_in[2];
    const int*   clas_tgts  = (const int*)d_in[3];
    const float* anchors    = (const float*)d_in[4];

    const int A  = in_sizes[4] / 4;
    const int Bn = in_sizes[1] / (A * 4);
    const int T  = in_sizes[3] / Bn;
    const int C  = in_sizes[0] / (Bn * A);
    const int C4 = C / 4;

    const int nblk = (A + SPAN - 1) / SPAN;

    // workspace: np_p | bb_p | cl_p, each float[B*nblk]
    char* ws = (char*)d_ws;
    float* np_p = (float*)ws;  ws += (size_t)Bn * nblk * sizeof(float);
    float* bb_p = (float*)ws;  ws += (size_t)Bn * nblk * sizeof(float);
    float* cl_p = (float*)ws;

    dim3 g1((unsigned)nblk, (unsigned)Bn);
    if (C4 == 20) {
        fused_kernel<20><<<g1, TPB, 0, stream>>>(
            bbox_preds, bbox_tgts, clas_tgts, anchors, clas_preds,
            A, T, C4, np_p, bb_p, cl_p, nblk);
    } else {
        fused_kernel<0><<<g1, TPB, 0, stream>>>(
            bbox_preds, bbox_tgts, clas_tgts, anchors, clas_preds,
            A, T, C4, np_p, bb_p, cl_p, nblk);
    }

    reduce_kernel<<<1, 1024, 0, stream>>>(np_p, bb_p, cl_p, nblk, Bn, (float*)d_out);
}